// Round 8
// baseline (67.217 us; speedup 1.0000x reference)
//
#include <hip/hip_runtime.h>

#define N_NODES   100000
#define N_EDGES   1600000
#define N_GRAPHS  256
#define D         32
#define GD        (N_GRAPHS * D)   // 8192
#define LSTRIDE   257              // lds[d*257+g]: banks (d+g)%32 spread
#define NBLK      512              // edge_stream blocks
#define SCALE_F   1048576.0f       // 2^20 fixed-point scale
#define INV_SCALE 9.5367431640625e-07f

// ---------- pass A: g8[e] = (u8) batch[src[e]] ----------
__global__ __launch_bounds__(1024) void g8_kernel(const int* __restrict__ src,
                                                  const int* __restrict__ batch,
                                                  unsigned char* __restrict__ g8) {
    const int stride = gridDim.x * blockDim.x;
    int i = blockIdx.x * blockDim.x + threadIdx.x;
    for (; i + 3 * stride < N_EDGES; i += 4 * stride) {
        const int s0 = src[i];
        const int s1 = src[i + stride];
        const int s2 = src[i + 2 * stride];
        const int s3 = src[i + 3 * stride];
        const int b0 = batch[s0], b1 = batch[s1], b2 = batch[s2], b3 = batch[s3];
        g8[i]              = (unsigned char)b0;
        g8[i + stride]     = (unsigned char)b1;
        g8[i + 2 * stride] = (unsigned char)b2;
        g8[i + 3 * stride] = (unsigned char)b3;
    }
    for (; i < N_EDGES; i += stride) g8[i] = (unsigned char)batch[src[i]];
}

// ---------- edge aggregation: stream ea in half-row pairs, int LDS accumulate ----------
// Unit h covers edge e = h>>2, cols c and c+4 (two float4 = half the row split
// low/high). One g8 byte per 32 floats. Rotating depth-1 prefetch keeps
// 4 x 16B loads in flight per lane while the LDS adds execute.
__global__ __launch_bounds__(1024) void edge_stream_kernel(
        const float* __restrict__ ea,
        const unsigned char* __restrict__ g8,
        int* __restrict__ epart /* [NBLK][GD], (g,d)-major */) {
    __shared__ int lds[D * LSTRIDE];               // 32.9 KB
    for (int i = threadIdx.x; i < D * LSTRIDE; i += 1024) lds[i] = 0;
    __syncthreads();

    const float4* __restrict__ ea4 = (const float4*)ea;
    const int total  = N_EDGES * 4;                // 6.4M half-row units
    const int stride = gridDim.x * blockDim.x;

    int h = blockIdx.x * blockDim.x + threadIdx.x;
    bool have = h < total;
    float4 vlo = make_float4(0.f, 0.f, 0.f, 0.f);
    float4 vhi = make_float4(0.f, 0.f, 0.f, 0.f);
    int g = 0, c4 = 0;
    if (have) {
        const int e = h >> 2, c = h & 3;
        vlo = ea4[e * 8 + c];                      // lanes 0-3: contiguous 64B
        vhi = ea4[e * 8 + c + 4];
        g = g8[e]; c4 = c * 4;
    }

    while (have) {
        const int hn = h + stride;
        const bool haven = hn < total;
        float4 vlon = make_float4(0.f, 0.f, 0.f, 0.f);
        float4 vhin = make_float4(0.f, 0.f, 0.f, 0.f);
        int gn = 0, c4n = 0;
        if (haven) {                                // issued before the adds below
            const int e = hn >> 2, c = hn & 3;
            vlon = ea4[e * 8 + c];
            vhin = ea4[e * 8 + c + 4];
            gn = g8[e]; c4n = c * 4;
        }

        const int blo = c4 * LSTRIDE + g;          // d = c*4 + j
        atomicAdd(&lds[blo              ], __float2int_rn(vlo.x * SCALE_F));
        atomicAdd(&lds[blo +     LSTRIDE], __float2int_rn(vlo.y * SCALE_F));
        atomicAdd(&lds[blo + 2 * LSTRIDE], __float2int_rn(vlo.z * SCALE_F));
        atomicAdd(&lds[blo + 3 * LSTRIDE], __float2int_rn(vlo.w * SCALE_F));
        const int bhi = blo + 16 * LSTRIDE;        // d = (c+4)*4 + j
        atomicAdd(&lds[bhi              ], __float2int_rn(vhi.x * SCALE_F));
        atomicAdd(&lds[bhi +     LSTRIDE], __float2int_rn(vhi.y * SCALE_F));
        atomicAdd(&lds[bhi + 2 * LSTRIDE], __float2int_rn(vhi.z * SCALE_F));
        atomicAdd(&lds[bhi + 3 * LSTRIDE], __float2int_rn(vhi.w * SCALE_F));

        h = hn; vlo = vlon; vhi = vhin; g = gn; c4 = c4n; have = haven;
    }
    __syncthreads();

    int* __restrict__ my = epart + (size_t)blockIdx.x * GD;
    for (int i = threadIdx.x; i < GD; i += 1024)
        my[i] = lds[(i & 31) * LSTRIDE + (i >> 5)];   // coalesced store, ≤2-way bank
}

// ---------- finish: node-range sum + epart column-sum + MLP, one block per graph ----------
__global__ __launch_bounds__(256) void finish_kernel(
        const float* __restrict__ x,
        const int* __restrict__ batch,
        const int* __restrict__ epart,    // [NBLK][GD]
        const float* __restrict__ u,
        const float* __restrict__ W,      // [3D][D]
        const float* __restrict__ bias,
        float* __restrict__ out) {
    const int g = blockIdx.x;
    __shared__ float  Ws[3 * D * D];               // 12 KB
    __shared__ float4 red[256];                    // 4 KB
    __shared__ int    ered[32][33];                // 4.2 KB, pad -> conflict-free cols
    __shared__ float  accN[D], accE[D], ush[D];

    for (int i = threadIdx.x; i < 3 * D * D; i += 256) Ws[i] = W[i];

    // node range of graph g (batch sorted)
    int lo = 0, hi = N_NODES;
    while (lo < hi) { const int m = (lo + hi) >> 1; if (batch[m] < g) lo = m + 1; else hi = m; }
    const int r0 = lo;
    hi = N_NODES;
    while (lo < hi) { const int m = (lo + hi) >> 1; if (batch[m] < g + 1) lo = m + 1; else hi = m; }
    const int r1 = lo;

    // ---- node sum: 32 row slots x 8 float4 cols ----
    {
        const int s = threadIdx.x >> 3;
        const int c = threadIdx.x & 7;
        const float4* __restrict__ x4 = (const float4*)x;
        float4 a = make_float4(0.f, 0.f, 0.f, 0.f);
        for (int r = r0 + s; r < r1; r += 32) {
            const float4 v = x4[r * 8 + c];
            a.x += v.x; a.y += v.y; a.z += v.z; a.w += v.w;
        }
        red[threadIdx.x] = a;
    }
    __syncthreads();
    if (threadIdx.x < 8) {
        float4 t = make_float4(0.f, 0.f, 0.f, 0.f);
        #pragma unroll
        for (int s2 = 0; s2 < 32; ++s2) {
            const float4 b = red[s2 * 8 + threadIdx.x];
            t.x += b.x; t.y += b.y; t.z += b.z; t.w += b.w;
        }
        ((float4*)accN)[threadIdx.x] = t;
    }

    // ---- epart column sum: 32 p-groups x 8 int4 cols, 16 int4 loads each ----
    {
        const int pgrp = threadIdx.x >> 3;         // 0..31
        const int q    = threadIdx.x & 7;          // int4 column
        const int4* __restrict__ ep4 = (const int4*)epart + (size_t)g * 8 + q;
        int4 s4 = make_int4(0, 0, 0, 0);
        for (int p = pgrp; p < NBLK; p += 32) {
            const int4 t = ep4[(size_t)p * (GD / 4)];
            s4.x += t.x; s4.y += t.y; s4.z += t.z; s4.w += t.w;
        }
        ered[pgrp][q * 4 + 0] = s4.x;
        ered[pgrp][q * 4 + 1] = s4.y;
        ered[pgrp][q * 4 + 2] = s4.z;
        ered[pgrp][q * 4 + 3] = s4.w;
    }
    __syncthreads();

    if (threadIdx.x < D) {
        const int d = threadIdx.x;
        int tot = 0;
        #pragma unroll
        for (int pg2 = 0; pg2 < 32; ++pg2) tot += ered[pg2][d];
        accE[d] = (float)tot * INV_SCALE;
        ush[d]  = u[g * D + d];
    }
    __syncthreads();

    if (threadIdx.x < D) {
        const int d = threadIdx.x;
        float sacc = bias[d];
        #pragma unroll
        for (int kk = 0; kk < D; ++kk) sacc += accN[kk] * Ws[kk * D + d];
        #pragma unroll
        for (int kk = 0; kk < D; ++kk) sacc += accE[kk] * Ws[(D + kk) * D + d];
        #pragma unroll
        for (int kk = 0; kk < D; ++kk) sacc += ush[kk] * Ws[(2 * D + kk) * D + d];
        out[g * D + d] = fmaxf(sacc, 0.f);
    }
}

extern "C" void kernel_launch(void* const* d_in, const int* in_sizes, int n_in,
                              void* d_out, int out_size, void* d_ws, size_t ws_size,
                              hipStream_t stream) {
    const float* x     = (const float*)d_in[0];
    const int*   ei    = (const int*)  d_in[1];    // [2][N_EDGES]; row 0 = src
    const float* ea    = (const float*)d_in[2];
    const float* u     = (const float*)d_in[3];
    const int*   batch = (const int*)  d_in[4];
    const float* W     = (const float*)d_in[5];
    const float* bias  = (const float*)d_in[6];
    float*       out   = (float*)d_out;

    // ws: [g8 1.6MB pad][epart NBLK*GD i32 = 16MB]
    const size_t g8_bytes = (size_t)((N_EDGES + 255) & ~255);
    unsigned char* g8    = (unsigned char*)d_ws;
    int*           epart = (int*)((char*)d_ws + g8_bytes);

    g8_kernel         <<<256, 1024, 0, stream>>>(ei, batch, g8);
    edge_stream_kernel<<<NBLK, 1024, 0, stream>>>(ea, g8, epart);
    finish_kernel     <<<N_GRAPHS, 256, 0, stream>>>(x, batch, epart, u, W, bias, out);
}

// Round 9
// 54.412 us; speedup vs baseline: 1.2353x; 1.2353x over previous
//
#include <hip/hip_runtime.h>

#define N_NODES   100000
#define N_EDGES   1600000
#define N_GRAPHS  256
#define D         32
#define GD        (N_GRAPHS * D)   // 8192
#define LSTRIDE   257              // lds[d*257+g]: banks (d+g)%32 spread
#define NBLK      256              // edge_stream blocks (1/CU, 16 waves)
#define NBG       256              // g8 sub-blocks inside pre_kernel
#define SCALE_F   1048576.0f       // 2^20 fixed-point scale
#define INV_SCALE 9.5367431640625e-07f

// ---------- pre: blocks [0,256) compute g8; blocks [256,512) node partials ----------
__global__ __launch_bounds__(1024) void pre_kernel(
        const int* __restrict__ src,
        const int* __restrict__ batch,
        unsigned char* __restrict__ g8,
        const float* __restrict__ x,
        float* __restrict__ npart /* [256][32] */) {
    if (blockIdx.x < NBG) {
        // ---- g8[e] = (u8) batch[src[e]] ----
        const int stride = NBG * 1024;
        int i = blockIdx.x * 1024 + threadIdx.x;
        for (; i + 3 * stride < N_EDGES; i += 4 * stride) {
            const int s0 = src[i];
            const int s1 = src[i + stride];
            const int s2 = src[i + 2 * stride];
            const int s3 = src[i + 3 * stride];
            const int b0 = batch[s0], b1 = batch[s1], b2 = batch[s2], b3 = batch[s3];
            g8[i]              = (unsigned char)b0;
            g8[i + stride]     = (unsigned char)b1;
            g8[i + 2 * stride] = (unsigned char)b2;
            g8[i + 3 * stride] = (unsigned char)b3;
        }
        for (; i < N_EDGES; i += stride) g8[i] = (unsigned char)batch[src[i]];
        return;
    }

    // ---- node partial for graph g (batch sorted -> contiguous range) ----
    const int g = blockIdx.x - NBG;
    int lo = 0, hi = N_NODES;
    while (lo < hi) { const int m = (lo + hi) >> 1; if (batch[m] < g) lo = m + 1; else hi = m; }
    const int r0 = lo;
    hi = N_NODES;
    while (lo < hi) { const int m = (lo + hi) >> 1; if (batch[m] < g + 1) lo = m + 1; else hi = m; }
    const int r1 = lo;

    const int s = threadIdx.x >> 3;      // 0..127 row slots
    const int c = threadIdx.x & 7;       // float4 column
    const float4* __restrict__ x4 = (const float4*)x;

    float4 a = make_float4(0.f, 0.f, 0.f, 0.f);
    for (int r = r0 + s; r < r1; r += 128) {
        const float4 v = x4[r * 8 + c];
        a.x += v.x; a.y += v.y; a.z += v.z; a.w += v.w;
    }

    __shared__ float4 red[1024];         // 16 KB
    red[threadIdx.x] = a;
    __syncthreads();
    if (threadIdx.x < 256) {
        float4 t = red[threadIdx.x];
        const float4 b1 = red[threadIdx.x + 256];
        const float4 b2 = red[threadIdx.x + 512];
        const float4 b3 = red[threadIdx.x + 768];
        t.x += b1.x + b2.x + b3.x; t.y += b1.y + b2.y + b3.y;
        t.z += b1.z + b2.z + b3.z; t.w += b1.w + b2.w + b3.w;
        red[threadIdx.x] = t;
    }
    __syncthreads();
    if (threadIdx.x < 8) {
        float4 t = make_float4(0.f, 0.f, 0.f, 0.f);
        #pragma unroll
        for (int s2 = 0; s2 < 32; ++s2) {
            const float4 b = red[s2 * 8 + threadIdx.x];
            t.x += b.x; t.y += b.y; t.z += b.z; t.w += b.w;
        }
        ((float4*)(npart + (size_t)g * D))[threadIdx.x] = t;
    }
}

// ---------- edge aggregation: stream ea (unit-stride), int fixed-point LDS accumulate ----------
// Depth-1 rotating pipeline: next iteration's loads issue BEFORE this
// iteration's LDS adds, so HBM latency overlaps the atomic work.
__global__ __launch_bounds__(1024) void edge_stream_kernel(
        const float* __restrict__ ea,
        const unsigned char* __restrict__ g8,
        int* __restrict__ epart /* [NBLK][GD], (g,d)-major */) {
    __shared__ int lds[D * LSTRIDE];               // 32.9 KB
    for (int i = threadIdx.x; i < D * LSTRIDE; i += 1024) lds[i] = 0;
    __syncthreads();

    const float4* __restrict__ ea4 = (const float4*)ea;
    const int total  = N_EDGES * (D / 4);          // 12.8M float4 units
    const int stride = gridDim.x * blockDim.x;     // 262144

    int icur = blockIdx.x * blockDim.x + threadIdx.x;
    bool have = icur < total;
    float4 v = make_float4(0.f, 0.f, 0.f, 0.f);
    int g = 0;
    if (have) { v = ea4[icur]; g = g8[icur >> 3]; }

    while (have) {
        const int inext = icur + stride;
        const bool haven = inext < total;
        float4 vn = make_float4(0.f, 0.f, 0.f, 0.f);
        int gn = 0;
        if (haven) { vn = ea4[inext]; gn = g8[inext >> 3]; }  // issued before adds

        const int base = ((icur & 7) * 4) * LSTRIDE + g;
        atomicAdd(&lds[base              ], __float2int_rn(v.x * SCALE_F));
        atomicAdd(&lds[base +     LSTRIDE], __float2int_rn(v.y * SCALE_F));
        atomicAdd(&lds[base + 2 * LSTRIDE], __float2int_rn(v.z * SCALE_F));
        atomicAdd(&lds[base + 3 * LSTRIDE], __float2int_rn(v.w * SCALE_F));

        icur = inext; v = vn; g = gn; have = haven;
    }
    __syncthreads();

    int* __restrict__ my = epart + (size_t)blockIdx.x * GD;
    for (int i = threadIdx.x; i < GD; i += 1024)
        my[i] = lds[(i & 31) * LSTRIDE + (i >> 5)];   // coalesced store, ≤2-way bank
}

// ---------- finish: epart column-sum (int4) + npart + MLP, one block per graph ----------
__global__ __launch_bounds__(256) void finish_kernel(
        const float* __restrict__ npart,  // [256][32]
        const int* __restrict__ epart,    // [NBLK][GD]
        const float* __restrict__ u,
        const float* __restrict__ W,      // [3D][D]
        const float* __restrict__ bias,
        float* __restrict__ out) {
    const int g = blockIdx.x;
    __shared__ float Ws[3 * D * D];                // 12 KB
    __shared__ int   ered[32][33];                 // pad -> conflict-free columns
    __shared__ float accN[D], accE[D], ush[D];

    for (int i = threadIdx.x; i < 3 * D * D; i += 256) Ws[i] = W[i];

    // ---- epart column sum: 32 p-groups x 8 int4 cols, 8 int4 loads each ----
    {
        const int pgrp = threadIdx.x >> 3;         // 0..31
        const int q    = threadIdx.x & 7;          // int4 column
        const int4* __restrict__ ep4 = (const int4*)epart + (size_t)g * 8 + q;
        int4 s4 = make_int4(0, 0, 0, 0);
        for (int p = pgrp; p < NBLK; p += 32) {
            const int4 t = ep4[(size_t)p * (GD / 4)];
            s4.x += t.x; s4.y += t.y; s4.z += t.z; s4.w += t.w;
        }
        ered[pgrp][q * 4 + 0] = s4.x;
        ered[pgrp][q * 4 + 1] = s4.y;
        ered[pgrp][q * 4 + 2] = s4.z;
        ered[pgrp][q * 4 + 3] = s4.w;
    }
    __syncthreads();

    if (threadIdx.x < D) {
        const int d = threadIdx.x;
        int tot = 0;
        #pragma unroll
        for (int pg2 = 0; pg2 < 32; ++pg2) tot += ered[pg2][d];
        accE[d] = (float)tot * INV_SCALE;
        accN[d] = npart[g * D + d];
        ush[d]  = u[g * D + d];
    }
    __syncthreads();

    if (threadIdx.x < D) {
        const int d = threadIdx.x;
        float sacc = bias[d];
        #pragma unroll
        for (int kk = 0; kk < D; ++kk) sacc += accN[kk] * Ws[kk * D + d];
        #pragma unroll
        for (int kk = 0; kk < D; ++kk) sacc += accE[kk] * Ws[(D + kk) * D + d];
        #pragma unroll
        for (int kk = 0; kk < D; ++kk) sacc += ush[kk] * Ws[(2 * D + kk) * D + d];
        out[g * D + d] = fmaxf(sacc, 0.f);
    }
}

extern "C" void kernel_launch(void* const* d_in, const int* in_sizes, int n_in,
                              void* d_out, int out_size, void* d_ws, size_t ws_size,
                              hipStream_t stream) {
    const float* x     = (const float*)d_in[0];
    const int*   ei    = (const int*)  d_in[1];    // [2][N_EDGES]; row 0 = src
    const float* ea    = (const float*)d_in[2];
    const float* u     = (const float*)d_in[3];
    const int*   batch = (const int*)  d_in[4];
    const float* W     = (const float*)d_in[5];
    const float* bias  = (const float*)d_in[6];
    float*       out   = (float*)d_out;

    // ws: [g8 1.6MB pad][npart GD f32][epart NBLK*GD i32 = 8MB]
    const size_t g8_bytes = (size_t)((N_EDGES + 255) & ~255);
    unsigned char* g8    = (unsigned char*)d_ws;
    float*         npart = (float*)((char*)d_ws + g8_bytes);
    int*           epart = (int*)(npart + GD);

    pre_kernel        <<<NBG + N_GRAPHS, 1024, 0, stream>>>(ei, batch, g8, x, npart);
    edge_stream_kernel<<<NBLK, 1024, 0, stream>>>(ea, g8, epart);
    finish_kernel     <<<N_GRAPHS, 256, 0, stream>>>(npart, epart, u, W, bias, out);
}

// Round 10
// 49.730 us; speedup vs baseline: 1.3517x; 1.0942x over previous
//
#include <hip/hip_runtime.h>

#define N_NODES   100000
#define N_EDGES   1600000
#define N_GRAPHS  256
#define D         32
#define GD        (N_GRAPHS * D)   // 8192
#define LSTRIDE   257              // lds[d*257+g]: banks (4c+j+g)%32 spread
#define NBLK      256              // 1 block/CU, 16 waves
#define SCALE_F   1048576.0f       // 2^20 fixed-point scale
#define INV_SCALE 9.5367431640625e-07f

// ---------- edge aggregation: stream ea, inline g = batch[src[e]], int LDS accumulate ----------
// 2-stage software pipeline per iteration k (unit i = i0 + k*S):
//   issue src for unit i+2S, batch[] for unit i+S (src loaded last iter),
//   ea4 for unit i+S, then the 4 LDS adds for unit i.
// Tail is branch-free: indices clamp to total-1, OOB values masked to 0.
__global__ __launch_bounds__(1024) void edge_stream_kernel(
        const float* __restrict__ ea,
        const int* __restrict__ src,
        const int* __restrict__ batch,
        int* __restrict__ epart /* [NBLK][GD], (g,d)-major */) {
    __shared__ int lds[D * LSTRIDE];               // 32.9 KB
    for (int i = threadIdx.x; i < D * LSTRIDE; i += 1024) lds[i] = 0;
    __syncthreads();

    const float4* __restrict__ ea4 = (const float4*)ea;
    const int total = N_EDGES * (D / 4);           // 12.8M float4 units
    const int S     = NBLK * 1024;                 // 262144
    const int i0    = blockIdx.x * 1024 + threadIdx.x;
    const int NIT   = (total + S - 1) / S;         // 49, uniform for all threads

    // prologue: fill pipeline for unit i0
    float4 vA; int gA, sA;
    {
        const int ic = min(i0, total - 1);
        const int st = src[ic >> 3];
        gA = batch[st];
        const float4 t = ea4[ic];
        const float m = (i0 < total) ? 1.f : 0.f;
        vA = make_float4(t.x * m, t.y * m, t.z * m, t.w * m);
        sA = src[min(i0 + S, total - 1) >> 3];     // src value for unit i0+S
    }

    int i = i0;
    for (int k = 0; k < NIT; ++k) {
        const int iS  = i + S;
        const int sB  = src[min(iS + S, total - 1) >> 3];   // unit i+2S
        const int gB  = batch[sA];                           // unit i+S (s from last iter)
        const float4 tv = ea4[min(iS, total - 1)];
        const float m = (iS < total) ? 1.f : 0.f;
        const float4 vB = make_float4(tv.x * m, tv.y * m, tv.z * m, tv.w * m);

        const int base = ((i & 7) * 4) * LSTRIDE + gA;
        atomicAdd(&lds[base              ], __float2int_rn(vA.x * SCALE_F));
        atomicAdd(&lds[base +     LSTRIDE], __float2int_rn(vA.y * SCALE_F));
        atomicAdd(&lds[base + 2 * LSTRIDE], __float2int_rn(vA.z * SCALE_F));
        atomicAdd(&lds[base + 3 * LSTRIDE], __float2int_rn(vA.w * SCALE_F));

        vA = vB; gA = gB; sA = sB; i = iS;
    }
    __syncthreads();

    int* __restrict__ my = epart + (size_t)blockIdx.x * GD;
    for (int j = threadIdx.x; j < GD; j += 1024)
        my[j] = lds[(j & 31) * LSTRIDE + (j >> 5)];   // coalesced, ≤2-way bank
}

// ---------- finish: node-range sum + epart column-sum + MLP, one block per graph ----------
__global__ __launch_bounds__(1024) void finish_kernel(
        const float* __restrict__ x,
        const int* __restrict__ batch,
        const int* __restrict__ epart,    // [NBLK][GD]
        const float* __restrict__ u,
        const float* __restrict__ W,      // [3D][D]
        const float* __restrict__ bias,
        float* __restrict__ out) {
    const int g = blockIdx.x;
    __shared__ float  Ws[3 * D * D];               // 12 KB
    __shared__ float4 red[1024];                   // 16 KB
    __shared__ int4   ered[128][9];                // 18.4 KB (pad col -> bank spread)
    __shared__ float  accN[D], accE[D], ush[D];

    for (int j = threadIdx.x; j < 3 * D * D; j += 1024) Ws[j] = W[j];
    if (threadIdx.x < D) ush[threadIdx.x] = u[g * D + threadIdx.x];

    // node range of graph g (batch sorted)
    int lo = 0, hi = N_NODES;
    while (lo < hi) { const int m = (lo + hi) >> 1; if (batch[m] < g) lo = m + 1; else hi = m; }
    const int r0 = lo;
    hi = N_NODES;
    while (lo < hi) { const int m = (lo + hi) >> 1; if (batch[m] < g + 1) lo = m + 1; else hi = m; }
    const int r1 = lo;

    // ---- node sum: 128 row slots x 8 float4 cols (~3 rows each) ----
    {
        const int s = threadIdx.x >> 3;
        const int c = threadIdx.x & 7;
        const float4* __restrict__ x4 = (const float4*)x;
        float4 a = make_float4(0.f, 0.f, 0.f, 0.f);
        for (int r = r0 + s; r < r1; r += 128) {
            const float4 v = x4[r * 8 + c];
            a.x += v.x; a.y += v.y; a.z += v.z; a.w += v.w;
        }
        red[threadIdx.x] = a;
    }

    // ---- epart partial: 128 p-groups x 8 int4 cols, 2 loads each ----
    {
        const int pg = threadIdx.x >> 3;
        const int q  = threadIdx.x & 7;
        const int4* __restrict__ ep4 = (const int4*)epart + (size_t)g * 8 + q;
        int4 s4 = ep4[(size_t)pg * (GD / 4)];
        const int4 t4 = ep4[(size_t)(pg + 128) * (GD / 4)];
        s4.x += t4.x; s4.y += t4.y; s4.z += t4.z; s4.w += t4.w;
        ered[pg][q] = s4;
    }
    __syncthreads();

    // ---- stage 2: red 1024->256, ered 128->32 (disjoint thread ranges) ----
    if (threadIdx.x < 256) {
        float4 t = red[threadIdx.x];
        const float4 b1 = red[threadIdx.x + 256];
        const float4 b2 = red[threadIdx.x + 512];
        const float4 b3 = red[threadIdx.x + 768];
        t.x += b1.x + b2.x + b3.x; t.y += b1.y + b2.y + b3.y;
        t.z += b1.z + b2.z + b3.z; t.w += b1.w + b2.w + b3.w;
        red[threadIdx.x] = t;
    } else if (threadIdx.x < 512) {
        const int t2 = threadIdx.x - 256;
        const int j = t2 >> 3, q = t2 & 7;         // j 0..31
        int4 s4 = ered[j][q];
        const int4 a1 = ered[j + 32][q];
        const int4 a2 = ered[j + 64][q];
        const int4 a3 = ered[j + 96][q];
        s4.x += a1.x + a2.x + a3.x; s4.y += a1.y + a2.y + a3.y;
        s4.z += a1.z + a2.z + a3.z; s4.w += a1.w + a2.w + a3.w;
        ered[j][q] = s4;
    }
    __syncthreads();

    // ---- stage 3: 32 slots -> final vectors ----
    if (threadIdx.x < 8) {                         // accN
        float4 t = make_float4(0.f, 0.f, 0.f, 0.f);
        #pragma unroll
        for (int s2 = 0; s2 < 32; ++s2) {
            const float4 b = red[s2 * 8 + threadIdx.x];
            t.x += b.x; t.y += b.y; t.z += b.z; t.w += b.w;
        }
        ((float4*)accN)[threadIdx.x] = t;
    } else if (threadIdx.x < 16) {                 // accE
        const int q = threadIdx.x - 8;
        int4 s4 = make_int4(0, 0, 0, 0);
        #pragma unroll
        for (int j = 0; j < 32; ++j) {
            const int4 b = ered[j][q];
            s4.x += b.x; s4.y += b.y; s4.z += b.z; s4.w += b.w;
        }
        accE[q * 4 + 0] = (float)s4.x * INV_SCALE;
        accE[q * 4 + 1] = (float)s4.y * INV_SCALE;
        accE[q * 4 + 2] = (float)s4.z * INV_SCALE;
        accE[q * 4 + 3] = (float)s4.w * INV_SCALE;
    }
    __syncthreads();

    if (threadIdx.x < D) {
        const int d = threadIdx.x;
        float sacc = bias[d];
        #pragma unroll
        for (int kk = 0; kk < D; ++kk) sacc += accN[kk] * Ws[kk * D + d];
        #pragma unroll
        for (int kk = 0; kk < D; ++kk) sacc += accE[kk] * Ws[(D + kk) * D + d];
        #pragma unroll
        for (int kk = 0; kk < D; ++kk) sacc += ush[kk] * Ws[(2 * D + kk) * D + d];
        out[g * D + d] = fmaxf(sacc, 0.f);
    }
}

extern "C" void kernel_launch(void* const* d_in, const int* in_sizes, int n_in,
                              void* d_out, int out_size, void* d_ws, size_t ws_size,
                              hipStream_t stream) {
    const float* x     = (const float*)d_in[0];
    const int*   ei    = (const int*)  d_in[1];    // [2][N_EDGES]; row 0 = src
    const float* ea    = (const float*)d_in[2];
    const float* u     = (const float*)d_in[3];
    const int*   batch = (const int*)  d_in[4];
    const float* W     = (const float*)d_in[5];
    const float* bias  = (const float*)d_in[6];
    float*       out   = (float*)d_out;

    int* epart = (int*)d_ws;                       // [NBLK][GD] i32 = 8 MB

    edge_stream_kernel<<<NBLK, 1024, 0, stream>>>(ea, ei, batch, epart);
    finish_kernel     <<<N_GRAPHS, 1024, 0, stream>>>(x, batch, epart, u, W, bias, out);
}